// Round 19
// baseline (346.923 us; speedup 1.0000x reference)
//
#include <hip/hip_runtime.h>
#include <cstdint>
#include <cmath>

typedef _Float16 f16;
using f16x8 = __attribute__((ext_vector_type(8))) _Float16;
using f16x4 = __attribute__((ext_vector_type(4))) _Float16;
using f32x4 = __attribute__((ext_vector_type(4))) float;

#define NHEAD 16
#define SEQ   2048
#define KSS   4            // K-split for k_stats
#define NEG_INF -3.0e38f

static __device__ __forceinline__ f32x4 mfma16(f16x8 a, f16x8 b, f32x4 c) {
    return __builtin_amdgcn_mfma_f32_16x16x32_f16(a, b, c, 0, 0, 0);
}

static __device__ __forceinline__ void gload16(const void* gp, void* lp) {
    __builtin_amdgcn_global_load_lds(
        (const __attribute__((address_space(1))) unsigned int*)gp,
        (__attribute__((address_space(3))) unsigned int*)lp, 16, 0, 0);
}

// ---------------- fused f32->f16 conversion (8 elems/thread) + RoPE table ----------------
__global__ __launch_bounds__(256) void k_cvt_all(
    const float* __restrict__ hsrc, const float* __restrict__ qdw, const float* __restrict__ kvdw,
    const float* __restrict__ quw, const float* __restrict__ kuw, const float* __restrict__ ow,
    f16* __restrict__ h16, f16* __restrict__ dw16, f16* __restrict__ quw16,
    f16* __restrict__ kuw16, f16* __restrict__ ow16, float* __restrict__ cs)
{
    constexpr int C1 = 524288;             // h: 4194304 elems / 8
    constexpr int C2 = C1 + 393216;        // qdw
    constexpr int C3 = C2 + 163840;        // kvdw (padded; 1179648 valid)
    constexpr int C4 = C3 + 589824;        // quw
    constexpr int C5 = C4 + 262144;        // kuw
    constexpr int C6 = C5 + 524288;        // ow;  rope range follows
    int chunk = blockIdx.x * 256 + threadIdx.x;
    if (chunk >= C6) {
        int idx = chunk - C6;              // 65536 rope entries
        if (idx < 65536) {
            int t = idx >> 5, j = idx & 31;
            float invf = (float)pow(10000.0, -(double)j / 32.0);
            float ang  = (float)t * invf;
            cs[t * 64 + j]      = (float)cos((double)ang);
            cs[t * 64 + 32 + j] = (float)sin((double)ang);
        }
        return;
    }
    const float* src; f16* dst; int off; int nvalid;
    if (chunk < C1)      { src = hsrc; dst = h16;  off = chunk;      nvalid = 4194304; }
    else if (chunk < C2) { src = qdw;  dst = dw16; off = chunk - C1; nvalid = 3145728; }
    else if (chunk < C3) { src = kvdw; dst = dw16 + 3145728; off = chunk - C2; nvalid = 1179648; }
    else if (chunk < C4) { src = quw;  dst = quw16; off = chunk - C3; nvalid = 4718592; }
    else if (chunk < C5) { src = kuw;  dst = kuw16; off = chunk - C4; nvalid = 2097152; }
    else                 { src = ow;   dst = ow16;  off = chunk - C5; nvalid = 4194304; }
    int i = off * 8;
    f16x8 o;
    if (i + 8 <= nvalid) {
        f32x4 a = *(const f32x4*)&src[i];
        f32x4 b = *(const f32x4*)&src[i + 4];
#pragma unroll
        for (int k = 0; k < 4; k++) { o[k] = (f16)a[k]; o[k + 4] = (f16)b[k]; }
    } else {
#pragma unroll
        for (int k = 0; k < 8; k++) {
            int idx = i + k;
            o[k] = (f16)((idx < nvalid) ? src[idx] : 0.f);
        }
    }
    *(f16x8*)&dst[i] = o;
}

// ---------------- GEMM body: BK=64, XOR-swizzled LDS (T2), single-buffered ----------------
template <typename OutT, bool NT>
static __device__ __forceinline__ void gemm_body(const f16* __restrict__ A, const f16* __restrict__ B,
                                                 OutT* __restrict__ C, int K, int ldc,
                                                 int m0, int n0, int k0, int k1,
                                                 f16* __restrict__ lds)
{
    const int tid  = threadIdx.x;
    const int lane = tid & 63;
    const int wv   = tid >> 6;
    const int l15  = lane & 15;
    const int lg   = lane >> 4;
    const int wm   = (wv >> 1) * 64;
    const int wn   = (wv & 1) * 64;

    f32x4 acc[4][4] = {};

    f16* As = lds;           // 8192 f16
    f16* Bs = lds + 8192;

    const int srow = tid >> 3;                  // 0..31
    const int g    = (tid & 7) ^ (srow & 7);
    const f16* ap = &A[(size_t)(m0 + srow) * K + g * 8];
    const f16* bp = &B[(size_t)(n0 + srow) * K + g * 8];
    const int ldst = wv * 512;

    for (int kt = k0; kt < k1; kt += 64) {
        __syncthreads();
#pragma unroll
        for (int p = 0; p < 4; p++) {
            gload16(ap + (size_t)(p * 32) * K + kt, As + p * 2048 + ldst);
            gload16(bp + (size_t)(p * 32) * K + kt, Bs + p * 2048 + ldst);
        }
        __syncthreads();
#pragma unroll
        for (int ki = 0; ki < 2; ki++) {
            f16x8 af[4], bf[4];
#pragma unroll
            for (int i = 0; i < 4; i++) {
                const int ar = wm + i * 16 + l15;
                af[i] = *(const f16x8*)&As[ar * 64 + (((ki * 4 + lg) ^ (ar & 7)) << 3)];
            }
#pragma unroll
            for (int i = 0; i < 4; i++) {
                const int br = wn + i * 16 + l15;
                bf[i] = *(const f16x8*)&Bs[br * 64 + (((ki * 4 + lg) ^ (br & 7)) << 3)];
            }
#pragma unroll
            for (int i = 0; i < 4; i++)
#pragma unroll
                for (int j = 0; j < 4; j++)
                    acc[i][j] = mfma16(af[i], bf[j], acc[i][j]);
        }
    }
#pragma unroll
    for (int i = 0; i < 4; i++) {
#pragma unroll
        for (int j = 0; j < 4; j++) {
            const int row = m0 + wm + i * 16 + lg * 4;
            const int col = n0 + wn + j * 16 + l15;
#pragma unroll
            for (int r = 0; r < 4; r++) {
                if constexpr (NT)
                    __builtin_nontemporal_store((OutT)acc[i][j][r], &C[(size_t)(row + r) * ldc + col]);
                else
                    C[(size_t)(row + r) * ldc + col] = (OutT)acc[i][j][r];
            }
        }
    }
}

template <typename OutT, bool NT, int SPLITK>
__global__ __launch_bounds__(256) void k_gemm(const f16* __restrict__ A, const f16* __restrict__ B,
                                              OutT* __restrict__ C, int K, int ldc, size_t zstride)
{
    __shared__ __align__(16) f16 lds[16384];
    const int ks   = (SPLITK > 1) ? (int)blockIdx.z : 0;
    const int ksub = K / SPLITK;
    gemm_body<OutT, NT>(A, B, C + (size_t)ks * zstride, K, ldc,
                        blockIdx.y * 128, blockIdx.x * 128, ks * ksub, ks * ksub + ksub, lds);
}

__global__ __launch_bounds__(256) void k_up_fused(const f16* __restrict__ cq, const f16* __restrict__ quw,
                                                  f16* __restrict__ q_all,
                                                  const f16* __restrict__ lat, const f16* __restrict__ kuw,
                                                  f16* __restrict__ kv_all)
{
    __shared__ __align__(16) f16 lds[16384];
    if (blockIdx.x < 24)
        gemm_body<f16, false>(cq, quw, q_all, 1536, 3072,
                              blockIdx.y * 128, blockIdx.x * 128, 0, 1536, lds);
    else
        gemm_body<f16, false>(lat, kuw, kv_all, 512, 4096,
                              blockIdx.y * 128, (blockIdx.x - 24) * 128, 0, 512, lds);
}

// ---------------- o_proj split-K combine (f16 partials -> f32 out) ----------------
__global__ __launch_bounds__(256) void k_add2f(const f16* __restrict__ p, float* __restrict__ out)
{
    size_t i = ((size_t)blockIdx.x * 256 + threadIdx.x) * 8;
    f16x8 a = *(const f16x8*)&p[i];
    f16x8 b = *(const f16x8*)&p[(size_t)2048 * 2048 + i];
    f32x4 o0, o1;
#pragma unroll
    for (int k = 0; k < 4; k++) {
        o0[k] = (float)a[k] + (float)b[k];
        o1[k] = (float)a[k + 4] + (float)b[k + 4];
    }
    __builtin_nontemporal_store(o0, (f32x4*)&out[i]);
    __builtin_nontemporal_store(o1, (f32x4*)&out[i + 4]);
}

// ---------------- fused RMS norms + down split-K combine (f16 partials) + k_pe rope ----------------
__global__ __launch_bounds__(256) void k_rms_both(const f16* __restrict__ P0, const f16* __restrict__ P1,
                                                  const float* __restrict__ wq, const float* __restrict__ wkv,
                                                  f16* __restrict__ cq, f16* __restrict__ lat,
                                                  f16* __restrict__ kro, const float* __restrict__ cs)
{
    const int row = blockIdx.x, tid = threadIdx.x;
    const f16* a = &P0[(size_t)row * 2176];
    const f16* b = &P1[(size_t)row * 2176];

    float v0[8], v1[8];
    float ssq = 0.f, ssk = 0.f;
    {
        f16x8 a8 = *(const f16x8*)&a[tid * 8];
        f16x8 b8 = *(const f16x8*)&b[tid * 8];
#pragma unroll
        for (int e = 0; e < 8; e++) {
            float v = (float)a8[e] + (float)b8[e];
            v0[e] = v;
            if (tid < 192) ssq += v * v; else ssk += v * v;
        }
    }
    if (tid < 8) {
        const int cc = 256 + tid;
        f16x8 a8 = *(const f16x8*)&a[cc * 8];
        f16x8 b8 = *(const f16x8*)&b[cc * 8];
#pragma unroll
        for (int e = 0; e < 8; e++) {
            float v = (float)a8[e] + (float)b8[e];
            v1[e] = v;
            ssk += v * v;
        }
    }
#pragma unroll
    for (int off = 32; off > 0; off >>= 1) {
        ssq += __shfl_xor(ssq, off);
        ssk += __shfl_xor(ssk, off);
    }
    __shared__ float part[4][2];
    if ((tid & 63) == 0) { part[tid >> 6][0] = ssq; part[tid >> 6][1] = ssk; }
    __syncthreads();
    float totq = part[0][0] + part[1][0] + part[2][0] + part[3][0];
    float totk = part[0][1] + part[1][1] + part[2][1] + part[3][1];
    float scq = 1.f / sqrtf(totq / 1536.f + 1e-6f);
    float sck = 1.f / sqrtf(totk / 576.f + 1e-6f);

    if (tid < 192) {
        f16x8 o;
#pragma unroll
        for (int e = 0; e < 8; e++) o[e] = (f16)(wq[tid * 8 + e] * v0[e] * scq);
        *(f16x8*)&cq[(size_t)row * 1536 + tid * 8] = o;
    } else {
        const int lc = (tid - 192) * 8;
        f16x8 o;
#pragma unroll
        for (int e = 0; e < 8; e++) o[e] = (f16)(wkv[lc + e] * v0[e] * sck);
        *(f16x8*)&lat[(size_t)row * 512 + lc] = o;
    }
    if (tid < 8) {
        float t[8];
#pragma unroll
        for (int e = 0; e < 8; e++) t[e] = wkv[512 + tid * 8 + e] * v1[e] * sck;
        const int j0 = tid * 4;
        f16x4 oc, os;
#pragma unroll
        for (int e2 = 0; e2 < 4; e2++) {
            const int j = j0 + e2;
            float cv = cs[row * 64 + j], sv = cs[row * 64 + 32 + j];
            oc[e2] = (f16)(t[2 * e2] * cv - t[2 * e2 + 1] * sv);
            os[e2] = (f16)(t[2 * e2 + 1] * cv + t[2 * e2] * sv);
        }
        *(f16x4*)&kro[row * 64 + j0]      = oc;
        *(f16x4*)&kro[row * 64 + 32 + j0] = os;
    }
}

// ---------------- fused assemble: Q (vectorized rope) + K_nope/V^T transpose ----------------
__global__ __launch_bounds__(256) void k_asm_all(const f16* __restrict__ q_all, const float* __restrict__ cs,
                                                 f16* __restrict__ Qf,
                                                 const f16* __restrict__ kv_all,
                                                 f16* __restrict__ Knope,  // [16][2048][128]
                                                 f16* __restrict__ Vt)     // [16][128][2048]
{
    __shared__ __align__(16) f16 Vs[128][136];
    const int tid = threadIdx.x;

    if (blockIdx.x < 3072) {
        const int gid = blockIdx.x * 256 + tid;
        const int p   = gid % 24;
        const int rowi = gid / 24;
        const int h = rowi >> 11, s = rowi & 2047;
        const f16* qrow = &q_all[(size_t)s * 3072 + h * 192];
        f16x8 o;
        if (p < 8) {
            const int pp = (p < 4) ? p : (p - 4);
            f16x8 la = *(const f16x8*)&qrow[128 + 16 * pp];
            f16x8 lb = *(const f16x8*)&qrow[136 + 16 * pp];
            const float* cb = &cs[s * 64 + 8 * pp];
#pragma unroll
            for (int e = 0; e < 8; e++) {
                float av = (float)((e < 4) ? la[2 * e] : lb[2 * e - 8]);
                float bv = (float)((e < 4) ? la[2 * e + 1] : lb[2 * e - 7]);
                float cv = cb[e], sv = cb[32 + e];
                o[e] = (f16)((p < 4) ? (av * cv - bv * sv) : (bv * cv + av * sv));
            }
        } else {
            o = *(const f16x8*)&qrow[8 * p - 64];
        }
        *(f16x8*)&Qf[((size_t)h * SEQ + s) * 192 + 8 * p] = o;
        return;
    }

    const int b  = blockIdx.x - 3072;
    const int s0 = (b & 15) * 128;
    const int h  = b >> 4;
#pragma unroll
    for (int i = 0; i < 16; i++) {
        const int c = tid + 256 * i;
        const int s_loc = c >> 5;
        const int g = c & 31;
        f16x8 v = *(const f16x8*)&kv_all[(size_t)(s0 + s_loc) * 4096 + h * 256 + g * 8];
        if (g < 16) {
            *(f16x8*)&Knope[((size_t)h * 2048 + s0 + s_loc) * 128 + g * 8] = v;
        } else {
            const int d0 = (g - 16) * 8;
#pragma unroll
            for (int k = 0; k < 8; k++) Vs[d0 + k][s_loc] = v[k];
        }
    }
    __syncthreads();
#pragma unroll
    for (int i = 0; i < 8; i++) {
        const int c = tid + 256 * i;
        const int d = c >> 4;
        const int gs = c & 15;
        f16x8 v = *(const f16x8*)&Vs[d][gs * 8];
        *(f16x8*)&Vt[((size_t)h * 128 + d) * 2048 + s0 + gs * 8] = v;
    }
}

// ---------------- attention 1/2: K-split partial exp-sums (shift-invariant softmax) ----------------
__global__ __launch_bounds__(256) void k_stats(
    const f16* __restrict__ Qf, const f16* __restrict__ Krope, const f16* __restrict__ Knope,
    float* __restrict__ lpart)
{
    const int h  = blockIdx.z;
    const int ks = blockIdx.y;
    const int qt = blockIdx.x;
    const int q0 = qt * 64;
    const int tid = threadIdx.x;
    const int lane = tid & 63;
    const int wv = tid >> 6;
    const int l15 = lane & 15;
    const int lg  = lane >> 4;
    const int rowb = q0 + wv * 16;

    __shared__ __align__(16) f16 Ks_[64][200];

    float l[4] = {0.f, 0.f, 0.f, 0.f};

    if (ks <= qt) {
        f16x8 qf[6];
        {
            const f16* qbase = &Qf[((size_t)h * SEQ + rowb + l15) * 192];
#pragma unroll
            for (int kf = 0; kf < 6; kf++)
                qf[kf] = *(const f16x8*)&qbase[kf * 32 + lg * 8];
        }
        const int srow = tid >> 2;
        const int sp4  = tid & 3;
        const f32x4 vzero = {0.f, 0.f, 0.f, 0.f};

        for (int t = ks; t <= qt; t += KSS) {
            const int c0 = t * 64;
            __syncthreads();
#pragma unroll
            for (int i = 0; i < 6; i++) {
                const int p = sp4 + 4 * i;
                f16x8 v;
                if (p < 8) v = *(const f16x8*)&Krope[(size_t)(c0 + srow) * 64 + p * 8];
                else       v = *(const f16x8*)&Knope[((size_t)h * SEQ + c0 + srow) * 128 + (p - 8) * 8];
                *(f16x8*)&Ks_[srow][p * 8] = v;
            }
            __syncthreads();

            f32x4 s[4];
#pragma unroll
            for (int ni = 0; ni < 4; ni++) {
                s[ni] = vzero;
                const f16* kp = &Ks_[ni * 16 + l15][0];
#pragma unroll
                for (int kf = 0; kf < 6; kf++)
                    s[ni] = mfma16(qf[kf], *(const f16x8*)&kp[kf * 32 + lg * 8], s[ni]);
            }

#pragma unroll
            for (int ni = 0; ni < 4; ni++) {
                const int col = c0 + ni * 16 + l15;
#pragma unroll
                for (int r = 0; r < 4; r++) {
                    const int row = rowb + lg * 4 + r;
                    l[r] += (col <= row) ? __expf(s[ni][r]) : 0.f;
                }
            }
        }
#pragma unroll
        for (int off = 1; off < 16; off <<= 1)
#pragma unroll
            for (int r = 0; r < 4; r++)
                l[r] += __shfl_xor(l[r], off);
    }

    if (l15 == 0) {
#pragma unroll
        for (int r = 0; r < 4; r++) {
            const int rin = wv * 16 + lg * 4 + r;
            lpart[(((size_t)h * 32 + qt) * KSS + ks) * 64 + rin] = l[r];
        }
    }
}

// ---------------- attention 2/2: P write (vectorized via Plds) + O; complementary qt pairing ----------------
__global__ __launch_bounds__(256) void k_pv(
    const f16* __restrict__ Qf, const f16* __restrict__ Krope, const f16* __restrict__ Knope,
    const f16* __restrict__ Vt, const float* __restrict__ lpart,
    float* __restrict__ attnw,    // [16][2048][2048] final P
    f16* __restrict__ Ohead)      // [2048][16*128]
{
    const int h  = blockIdx.y;
    const int qt = (h >= 8) ? (31 - (int)blockIdx.x) : (int)blockIdx.x;
    const int q0 = qt * 64;
    const int tid = threadIdx.x;
    const int lane = tid & 63;
    const int wv = tid >> 6;
    const int l15 = lane & 15;
    const int lg  = lane >> 4;
    const int rowb = q0 + wv * 16;

    __shared__ __align__(16) f16 Ks_[64][200];
    __shared__ __align__(16) f16 Vs[128][72];
    __shared__ __align__(16) f16 Plds[4][16][72];

    f16x8 qf[6];
    {
        const f16* qbase = &Qf[((size_t)h * SEQ + rowb + l15) * 192];
#pragma unroll
        for (int kf = 0; kf < 6; kf++)
            qf[kf] = *(const f16x8*)&qbase[kf * 32 + lg * 8];
    }

    float rlr[4];
    {
        const float* base = &lpart[(((size_t)h * 32 + qt) * KSS) * 64];
#pragma unroll
        for (int r = 0; r < 4; r++) {
            const int rin = wv * 16 + lg * 4 + r;
            float ll = 0.f;
#pragma unroll
            for (int k2 = 0; k2 < KSS; k2++) ll += base[k2 * 64 + rin];
            rlr[r] = 1.f / ll;
        }
    }

    f32x4 o[8] = {};
    const f32x4 vzero = {0.f, 0.f, 0.f, 0.f};
    const int srow = tid >> 2;
    const int sp4  = tid & 3;
    const int prow = lane >> 2;       // 0..15 (P store-back row)
    const int pc4  = lane & 3;        // chunk group

    for (int t = 0; t <= qt; t++) {
        const int c0 = t * 64;
        __syncthreads();
#pragma unroll
        for (int i = 0; i < 6; i++) {
            const int p = sp4 + 4 * i;
            f16x8 v;
            if (p < 8) v = *(const f16x8*)&Krope[(size_t)(c0 + srow) * 64 + p * 8];
            else       v = *(const f16x8*)&Knope[((size_t)h * SEQ + c0 + srow) * 128 + (p - 8) * 8];
            *(f16x8*)&Ks_[srow][p * 8] = v;
        }
#pragma unroll
        for (int i = 0; i < 4; i++) {
            const int c = tid + 256 * i;
            const int d = c >> 3, x = c & 7;
            *(f16x8*)&Vs[d][x * 8] = *(const f16x8*)&Vt[((size_t)h * 128 + d) * SEQ + c0 + x * 8];
        }
        __syncthreads();

        f32x4 s[4];
#pragma unroll
        for (int ni = 0; ni < 4; ni++) {
            s[ni] = vzero;
            const f16* kp = &Ks_[ni * 16 + l15][0];
#pragma unroll
            for (int kf = 0; kf < 6; kf++)
                s[ni] = mfma16(qf[kf], *(const f16x8*)&kp[kf * 32 + lg * 8], s[ni]);
        }

        // P -> Plds (f16, masked zeros included)
#pragma unroll
        for (int ni = 0; ni < 4; ni++) {
            const int col = c0 + ni * 16 + l15;
#pragma unroll
            for (int r = 0; r < 4; r++) {
                const int row = rowb + lg * 4 + r;
                float p = (col <= row) ? __expf(s[ni][r]) * rlr[r] : 0.f;
                Plds[wv][lg * 4 + r][ni * 16 + l15] = (f16)p;
            }
        }
        asm volatile("" ::: "memory");

        // vectorized P store: lane handles row prow, 4 chunks of 4 cols (f32x4 each)
        {
            float* rowp = &attnw[((size_t)h * SEQ + rowb + prow) * SEQ + c0];
#pragma unroll
            for (int it = 0; it < 4; it++) {
                const int cc = (pc4 + it * 4) * 4;      // 0..60 step 4
                f16x4 pv4 = *(const f16x4*)&Plds[wv][prow][cc];
                f32x4 o4;
#pragma unroll
                for (int e = 0; e < 4; e++) o4[e] = (float)pv4[e];
                __builtin_nontemporal_store(o4, (f32x4*)&rowp[cc]);
            }
        }

        f16x8 pa0 = *(const f16x8*)&Plds[wv][l15][lg * 8];
        f16x8 pa1 = *(const f16x8*)&Plds[wv][l15][32 + lg * 8];
#pragma unroll
        for (int nd = 0; nd < 8; nd++) {
            const f16* vp = &Vs[nd * 16 + l15][lg * 8];
            o[nd] = mfma16(pa0, *(const f16x8*)&vp[0],  o[nd]);
            o[nd] = mfma16(pa1, *(const f16x8*)&vp[32], o[nd]);
        }
    }

#pragma unroll
    for (int nd = 0; nd < 8; nd++)
#pragma unroll
        for (int r = 0; r < 4; r++) {
            const int row = rowb + lg * 4 + r;
            Ohead[(size_t)row * 2048 + h * 128 + nd * 16 + l15] = (f16)o[nd][r];
        }

    // zero-fill cols >= q0+64 (wave-contiguous chunk layout)
    {
        const int cstart = q0 + 64;
        const int zc = SEQ - cstart;
        if (zc > 0) {
            const int nchunk = zc >> 2;
            for (int i = tid; i < 64 * nchunk; i += 256) {
                const int r  = i / nchunk;
                const int cc = (i - r * nchunk) << 2;
                __builtin_nontemporal_store(vzero,
                    (f32x4*)&attnw[((size_t)h * SEQ + q0 + r) * SEQ + cstart + cc]);
            }
        }
    }
}

extern "C" void kernel_launch(void* const* d_in, const int* in_sizes, int n_in,
                              void* d_out, int out_size, void* d_ws, size_t ws_size,
                              hipStream_t stream)
{
    (void)in_sizes; (void)n_in; (void)out_size; (void)ws_size;
    const float* hidden    = (const float*)d_in[0];
    const float* q_down_w  = (const float*)d_in[3];
    const float* kv_down_w = (const float*)d_in[4];
    const float* q_up_w    = (const float*)d_in[5];
    const float* k_up_w    = (const float*)d_in[6];
    const float* o_w       = (const float*)d_in[7];
    const float* q_norm_w  = (const float*)d_in[8];
    const float* kv_norm_w = (const float*)d_in[9];

    float* attnw = (float*)d_out;                        // 16*2048*2048 f32
    float* outp  = attnw + (size_t)NHEAD * SEQ * SEQ;    // 2048*2048 f32

    // ---- ws layout ----
    char* wp = (char*)d_ws;
    auto aws = [&](size_t bytes) { void* p = (void*)wp; wp += (bytes + 255) & ~(size_t)255; return p; };
    f16*  ow16  = (f16*)aws((size_t)2048 * 2048 * 2);
    f16*  Ohead = (f16*)aws((size_t)2048 * 2048 * 2);
    // dead-before-o_proj region starts here (aliased by opp):
    f16*  Qf    = (f16*)aws((size_t)16 * 2048 * 192 * 2);
    f16*  Knope = (f16*)aws((size_t)16 * 2048 * 128 * 2);
    f16*  Vt    = (f16*)aws((size_t)16 * 128 * 2048 * 2);
    f16*  Krope = (f16*)aws((size_t)2048 * 64 * 2);
    float* cs   = (float*)aws((size_t)2048 * 64 * 4);
    float* lpart  = (float*)aws((size_t)16 * 32 * KSS * 64 * 4);
    f16*  opp    = (f16*)Qf;   // o_proj split-K(2) partials f16 (16.8 MB < dead region)

    // ---- early-pipeline scratch inside d_out attn region ----
    char* sp = (char*)d_out;
    auto aso = [&](size_t bytes) { void* p = (void*)sp; sp += (bytes + 255) & ~(size_t)255; return p; };
    f16*  h16      = (f16*)aso((size_t)2048 * 2048 * 2);
    f16*  dw16     = (f16*)aso((size_t)2176 * 2048 * 2);
    f16*  quw16    = (f16*)aso((size_t)3072 * 1536 * 2);
    f16*  kuw16    = (f16*)aso((size_t)4096 * 512 * 2);
    f16*  down_part = (f16*)aso((size_t)2 * 2048 * 2176 * 2);  // f16 split-K(2) partials
    f16*  cq16     = (f16*)aso((size_t)2048 * 1536 * 2);
    f16*  latent16 = (f16*)aso((size_t)2048 * 512 * 2);
    f16*  q_all    = (f16*)aso((size_t)2048 * 3072 * 2);
    f16*  kv_all   = (f16*)aso((size_t)2048 * 4096 * 2);

    // conversions + rope table, one launch (8 elems/thread)
    k_cvt_all<<<dim3(9856), dim3(256), 0, stream>>>(
        hidden, q_down_w, kv_down_w, q_up_w, k_up_w, o_w,
        h16, dw16, quw16, kuw16, ow16, cs);

    // fused down-projection, split-K=2: f16 partials [2][2048][2176]
    k_gemm<f16, false, 2><<<dim3(17, 16, 2), dim3(256), 0, stream>>>(
        h16, dw16, down_part, 2048, 2176, (size_t)2048 * 2176);

    k_rms_both<<<dim3(2048), dim3(256), 0, stream>>>(
        down_part, down_part + (size_t)2048 * 2176, q_norm_w, kv_norm_w,
        cq16, latent16, Krope, cs);

    k_up_fused<<<dim3(56, 16), dim3(256), 0, stream>>>(cq16, quw16, q_all, latent16, kuw16, kv_all);

    // fused Q-assembly + KV-assembly
    k_asm_all<<<dim3(3072 + 256), dim3(256), 0, stream>>>(q_all, cs, Qf, kv_all, Knope, Vt);

    // attention: exp-sums(KSS=4) -> P+O (single-pass K, staged V, paired qt)
    k_stats<<<dim3(32, KSS, 16), dim3(256), 0, stream>>>(Qf, Krope, Knope, lpart);
    k_pv<<<dim3(32, 16), dim3(256), 0, stream>>>(Qf, Krope, Knope, Vt, lpart, attnw, Ohead);

    // output projection, split-K=2 into f16 opp, then combine to f32 outp
    k_gemm<f16, false, 2><<<dim3(16, 16, 2), dim3(256), 0, stream>>>(
        Ohead, ow16, opp, 2048, 2048, (size_t)2048 * 2048);
    k_add2f<<<dim3(2048), dim3(256), 0, stream>>>(opp, outp);
}

// Round 20
// 309.345 us; speedup vs baseline: 1.1215x; 1.1215x over previous
//
#include <hip/hip_runtime.h>
#include <cstdint>
#include <cmath>

typedef _Float16 f16;
using f16x8 = __attribute__((ext_vector_type(8))) _Float16;
using f16x4 = __attribute__((ext_vector_type(4))) _Float16;
using f32x4 = __attribute__((ext_vector_type(4))) float;

#define NHEAD 16
#define SEQ   2048
#define KSS   4            // K-split for k_stats
#define NEG_INF -3.0e38f

static __device__ __forceinline__ f32x4 mfma16(f16x8 a, f16x8 b, f32x4 c) {
    return __builtin_amdgcn_mfma_f32_16x16x32_f16(a, b, c, 0, 0, 0);
}

static __device__ __forceinline__ void gload16(const void* gp, void* lp) {
    __builtin_amdgcn_global_load_lds(
        (const __attribute__((address_space(1))) unsigned int*)gp,
        (__attribute__((address_space(3))) unsigned int*)lp, 16, 0, 0);
}

// ---------------- fused f32->f16 conversion (8 elems/thread) + RoPE table ----------------
__global__ __launch_bounds__(256) void k_cvt_all(
    const float* __restrict__ hsrc, const float* __restrict__ qdw, const float* __restrict__ kvdw,
    const float* __restrict__ quw, const float* __restrict__ kuw, const float* __restrict__ ow,
    f16* __restrict__ h16, f16* __restrict__ dw16, f16* __restrict__ quw16,
    f16* __restrict__ kuw16, f16* __restrict__ ow16, float* __restrict__ cs)
{
    constexpr int C1 = 524288;             // h: 4194304 elems / 8
    constexpr int C2 = C1 + 393216;        // qdw
    constexpr int C3 = C2 + 163840;        // kvdw (padded; 1179648 valid)
    constexpr int C4 = C3 + 589824;        // quw
    constexpr int C5 = C4 + 262144;        // kuw
    constexpr int C6 = C5 + 524288;        // ow;  rope range follows
    int chunk = blockIdx.x * 256 + threadIdx.x;
    if (chunk >= C6) {
        int idx = chunk - C6;              // 65536 rope entries
        if (idx < 65536) {
            int t = idx >> 5, j = idx & 31;
            float invf = (float)pow(10000.0, -(double)j / 32.0);
            float ang  = (float)t * invf;
            cs[t * 64 + j]      = (float)cos((double)ang);
            cs[t * 64 + 32 + j] = (float)sin((double)ang);
        }
        return;
    }
    const float* src; f16* dst; int off; int nvalid;
    if (chunk < C1)      { src = hsrc; dst = h16;  off = chunk;      nvalid = 4194304; }
    else if (chunk < C2) { src = qdw;  dst = dw16; off = chunk - C1; nvalid = 3145728; }
    else if (chunk < C3) { src = kvdw; dst = dw16 + 3145728; off = chunk - C2; nvalid = 1179648; }
    else if (chunk < C4) { src = quw;  dst = quw16; off = chunk - C3; nvalid = 4718592; }
    else if (chunk < C5) { src = kuw;  dst = kuw16; off = chunk - C4; nvalid = 2097152; }
    else                 { src = ow;   dst = ow16;  off = chunk - C5; nvalid = 4194304; }
    int i = off * 8;
    f16x8 o;
    if (i + 8 <= nvalid) {
        f32x4 a = *(const f32x4*)&src[i];
        f32x4 b = *(const f32x4*)&src[i + 4];
#pragma unroll
        for (int k = 0; k < 4; k++) { o[k] = (f16)a[k]; o[k + 4] = (f16)b[k]; }
    } else {
#pragma unroll
        for (int k = 0; k < 8; k++) {
            int idx = i + k;
            o[k] = (f16)((idx < nvalid) ? src[idx] : 0.f);
        }
    }
    *(f16x8*)&dst[i] = o;
}

// ---------------- GEMM body: BK=64, XOR-swizzled LDS (T2), single-buffered ----------------
template <typename OutT, bool NT>
static __device__ __forceinline__ void gemm_body(const f16* __restrict__ A, const f16* __restrict__ B,
                                                 OutT* __restrict__ C, int K, int ldc,
                                                 int m0, int n0, int k0, int k1,
                                                 f16* __restrict__ lds)
{
    const int tid  = threadIdx.x;
    const int lane = tid & 63;
    const int wv   = tid >> 6;
    const int l15  = lane & 15;
    const int lg   = lane >> 4;
    const int wm   = (wv >> 1) * 64;
    const int wn   = (wv & 1) * 64;

    f32x4 acc[4][4] = {};

    f16* As = lds;           // 8192 f16
    f16* Bs = lds + 8192;

    const int srow = tid >> 3;                  // 0..31
    const int g    = (tid & 7) ^ (srow & 7);
    const f16* ap = &A[(size_t)(m0 + srow) * K + g * 8];
    const f16* bp = &B[(size_t)(n0 + srow) * K + g * 8];
    const int ldst = wv * 512;

    for (int kt = k0; kt < k1; kt += 64) {
        __syncthreads();
#pragma unroll
        for (int p = 0; p < 4; p++) {
            gload16(ap + (size_t)(p * 32) * K + kt, As + p * 2048 + ldst);
            gload16(bp + (size_t)(p * 32) * K + kt, Bs + p * 2048 + ldst);
        }
        __syncthreads();
#pragma unroll
        for (int ki = 0; ki < 2; ki++) {
            f16x8 af[4], bf[4];
#pragma unroll
            for (int i = 0; i < 4; i++) {
                const int ar = wm + i * 16 + l15;
                af[i] = *(const f16x8*)&As[ar * 64 + (((ki * 4 + lg) ^ (ar & 7)) << 3)];
            }
#pragma unroll
            for (int i = 0; i < 4; i++) {
                const int br = wn + i * 16 + l15;
                bf[i] = *(const f16x8*)&Bs[br * 64 + (((ki * 4 + lg) ^ (br & 7)) << 3)];
            }
#pragma unroll
            for (int i = 0; i < 4; i++)
#pragma unroll
                for (int j = 0; j < 4; j++)
                    acc[i][j] = mfma16(af[i], bf[j], acc[i][j]);
        }
    }
#pragma unroll
    for (int i = 0; i < 4; i++) {
#pragma unroll
        for (int j = 0; j < 4; j++) {
            const int row = m0 + wm + i * 16 + lg * 4;
            const int col = n0 + wn + j * 16 + l15;
#pragma unroll
            for (int r = 0; r < 4; r++) {
                if constexpr (NT)
                    __builtin_nontemporal_store((OutT)acc[i][j][r], &C[(size_t)(row + r) * ldc + col]);
                else
                    C[(size_t)(row + r) * ldc + col] = (OutT)acc[i][j][r];
            }
        }
    }
}

template <typename OutT, bool NT, int SPLITK>
__global__ __launch_bounds__(256) void k_gemm(const f16* __restrict__ A, const f16* __restrict__ B,
                                              OutT* __restrict__ C, int K, int ldc, size_t zstride)
{
    __shared__ __align__(16) f16 lds[16384];
    const int ks   = (SPLITK > 1) ? (int)blockIdx.z : 0;
    const int ksub = K / SPLITK;
    gemm_body<OutT, NT>(A, B, C + (size_t)ks * zstride, K, ldc,
                        blockIdx.y * 128, blockIdx.x * 128, ks * ksub, ks * ksub + ksub, lds);
}

__global__ __launch_bounds__(256) void k_up_fused(const f16* __restrict__ cq, const f16* __restrict__ quw,
                                                  f16* __restrict__ q_all,
                                                  const f16* __restrict__ lat, const f16* __restrict__ kuw,
                                                  f16* __restrict__ kv_all)
{
    __shared__ __align__(16) f16 lds[16384];
    if (blockIdx.x < 24)
        gemm_body<f16, false>(cq, quw, q_all, 1536, 3072,
                              blockIdx.y * 128, blockIdx.x * 128, 0, 1536, lds);
    else
        gemm_body<f16, false>(lat, kuw, kv_all, 512, 4096,
                              blockIdx.y * 128, (blockIdx.x - 24) * 128, 0, 512, lds);
}

// ---------------- o_proj split-K combine (f16 partials -> f32 out) ----------------
__global__ __launch_bounds__(256) void k_add2f(const f16* __restrict__ p, float* __restrict__ out)
{
    size_t i = ((size_t)blockIdx.x * 256 + threadIdx.x) * 8;
    f16x8 a = *(const f16x8*)&p[i];
    f16x8 b = *(const f16x8*)&p[(size_t)2048 * 2048 + i];
    f32x4 o0, o1;
#pragma unroll
    for (int k = 0; k < 4; k++) {
        o0[k] = (float)a[k] + (float)b[k];
        o1[k] = (float)a[k + 4] + (float)b[k + 4];
    }
    __builtin_nontemporal_store(o0, (f32x4*)&out[i]);
    __builtin_nontemporal_store(o1, (f32x4*)&out[i + 4]);
}

// ---------------- fused RMS norms + down split-K combine (f16 partials) + k_pe rope ----------------
__global__ __launch_bounds__(256) void k_rms_both(const f16* __restrict__ P0, const f16* __restrict__ P1,
                                                  const float* __restrict__ wq, const float* __restrict__ wkv,
                                                  f16* __restrict__ cq, f16* __restrict__ lat,
                                                  f16* __restrict__ kro, const float* __restrict__ cs)
{
    const int row = blockIdx.x, tid = threadIdx.x;
    const f16* a = &P0[(size_t)row * 2176];
    const f16* b = &P1[(size_t)row * 2176];

    float v0[8], v1[8];
    float ssq = 0.f, ssk = 0.f;
    {
        f16x8 a8 = *(const f16x8*)&a[tid * 8];
        f16x8 b8 = *(const f16x8*)&b[tid * 8];
#pragma unroll
        for (int e = 0; e < 8; e++) {
            float v = (float)a8[e] + (float)b8[e];
            v0[e] = v;
            if (tid < 192) ssq += v * v; else ssk += v * v;
        }
    }
    if (tid < 8) {
        const int cc = 256 + tid;
        f16x8 a8 = *(const f16x8*)&a[cc * 8];
        f16x8 b8 = *(const f16x8*)&b[cc * 8];
#pragma unroll
        for (int e = 0; e < 8; e++) {
            float v = (float)a8[e] + (float)b8[e];
            v1[e] = v;
            ssk += v * v;
        }
    }
#pragma unroll
    for (int off = 32; off > 0; off >>= 1) {
        ssq += __shfl_xor(ssq, off);
        ssk += __shfl_xor(ssk, off);
    }
    __shared__ float part[4][2];
    if ((tid & 63) == 0) { part[tid >> 6][0] = ssq; part[tid >> 6][1] = ssk; }
    __syncthreads();
    float totq = part[0][0] + part[1][0] + part[2][0] + part[3][0];
    float totk = part[0][1] + part[1][1] + part[2][1] + part[3][1];
    float scq = 1.f / sqrtf(totq / 1536.f + 1e-6f);
    float sck = 1.f / sqrtf(totk / 576.f + 1e-6f);

    if (tid < 192) {
        f16x8 o;
#pragma unroll
        for (int e = 0; e < 8; e++) o[e] = (f16)(wq[tid * 8 + e] * v0[e] * scq);
        *(f16x8*)&cq[(size_t)row * 1536 + tid * 8] = o;
    } else {
        const int lc = (tid - 192) * 8;
        f16x8 o;
#pragma unroll
        for (int e = 0; e < 8; e++) o[e] = (f16)(wkv[lc + e] * v0[e] * sck);
        *(f16x8*)&lat[(size_t)row * 512 + lc] = o;
    }
    if (tid < 8) {
        float t[8];
#pragma unroll
        for (int e = 0; e < 8; e++) t[e] = wkv[512 + tid * 8 + e] * v1[e] * sck;
        const int j0 = tid * 4;
        f16x4 oc, os;
#pragma unroll
        for (int e2 = 0; e2 < 4; e2++) {
            const int j = j0 + e2;
            float cv = cs[row * 64 + j], sv = cs[row * 64 + 32 + j];
            oc[e2] = (f16)(t[2 * e2] * cv - t[2 * e2 + 1] * sv);
            os[e2] = (f16)(t[2 * e2 + 1] * cv + t[2 * e2] * sv);
        }
        *(f16x4*)&kro[row * 64 + j0]      = oc;
        *(f16x4*)&kro[row * 64 + 32 + j0] = os;
    }
}

// ---------------- fused assemble: Q (vectorized rope) + K_nope/V^T transpose ----------------
__global__ __launch_bounds__(256) void k_asm_all(const f16* __restrict__ q_all, const float* __restrict__ cs,
                                                 f16* __restrict__ Qf,
                                                 const f16* __restrict__ kv_all,
                                                 f16* __restrict__ Knope,  // [16][2048][128]
                                                 f16* __restrict__ Vt)     // [16][128][2048]
{
    __shared__ __align__(16) f16 Vs[128][136];
    const int tid = threadIdx.x;

    if (blockIdx.x < 3072) {
        const int gid = blockIdx.x * 256 + tid;
        const int p   = gid % 24;
        const int rowi = gid / 24;
        const int h = rowi >> 11, s = rowi & 2047;
        const f16* qrow = &q_all[(size_t)s * 3072 + h * 192];
        f16x8 o;
        if (p < 8) {
            const int pp = (p < 4) ? p : (p - 4);
            f16x8 la = *(const f16x8*)&qrow[128 + 16 * pp];
            f16x8 lb = *(const f16x8*)&qrow[136 + 16 * pp];
            const float* cb = &cs[s * 64 + 8 * pp];
#pragma unroll
            for (int e = 0; e < 8; e++) {
                float av = (float)((e < 4) ? la[2 * e] : lb[2 * e - 8]);
                float bv = (float)((e < 4) ? la[2 * e + 1] : lb[2 * e - 7]);
                float cv = cb[e], sv = cb[32 + e];
                o[e] = (f16)((p < 4) ? (av * cv - bv * sv) : (bv * cv + av * sv));
            }
        } else {
            o = *(const f16x8*)&qrow[8 * p - 64];
        }
        *(f16x8*)&Qf[((size_t)h * SEQ + s) * 192 + 8 * p] = o;
        return;
    }

    const int b  = blockIdx.x - 3072;
    const int s0 = (b & 15) * 128;
    const int h  = b >> 4;
#pragma unroll
    for (int i = 0; i < 16; i++) {
        const int c = tid + 256 * i;
        const int s_loc = c >> 5;
        const int g = c & 31;
        f16x8 v = *(const f16x8*)&kv_all[(size_t)(s0 + s_loc) * 4096 + h * 256 + g * 8];
        if (g < 16) {
            *(f16x8*)&Knope[((size_t)h * 2048 + s0 + s_loc) * 128 + g * 8] = v;
        } else {
            const int d0 = (g - 16) * 8;
#pragma unroll
            for (int k = 0; k < 8; k++) Vs[d0 + k][s_loc] = v[k];
        }
    }
    __syncthreads();
#pragma unroll
    for (int i = 0; i < 8; i++) {
        const int c = tid + 256 * i;
        const int d = c >> 4;
        const int gs = c & 15;
        f16x8 v = *(const f16x8*)&Vs[d][gs * 8];
        *(f16x8*)&Vt[((size_t)h * 128 + d) * 2048 + s0 + gs * 8] = v;
    }
}

// ---------------- attention 1/2: K-split partial exp-sums (shift-invariant softmax) ----------------
__global__ __launch_bounds__(256) void k_stats(
    const f16* __restrict__ Qf, const f16* __restrict__ Krope, const f16* __restrict__ Knope,
    float* __restrict__ lpart)
{
    const int h  = blockIdx.z;
    const int ks = blockIdx.y;
    const int qt = blockIdx.x;
    const int q0 = qt * 64;
    const int tid = threadIdx.x;
    const int lane = tid & 63;
    const int wv = tid >> 6;
    const int l15 = lane & 15;
    const int lg  = lane >> 4;
    const int rowb = q0 + wv * 16;

    __shared__ __align__(16) f16 Ks_[64][200];

    float l[4] = {0.f, 0.f, 0.f, 0.f};

    if (ks <= qt) {
        f16x8 qf[6];
        {
            const f16* qbase = &Qf[((size_t)h * SEQ + rowb + l15) * 192];
#pragma unroll
            for (int kf = 0; kf < 6; kf++)
                qf[kf] = *(const f16x8*)&qbase[kf * 32 + lg * 8];
        }
        const int srow = tid >> 2;
        const int sp4  = tid & 3;
        const f32x4 vzero = {0.f, 0.f, 0.f, 0.f};

        for (int t = ks; t <= qt; t += KSS) {
            const int c0 = t * 64;
            __syncthreads();
#pragma unroll
            for (int i = 0; i < 6; i++) {
                const int p = sp4 + 4 * i;
                f16x8 v;
                if (p < 8) v = *(const f16x8*)&Krope[(size_t)(c0 + srow) * 64 + p * 8];
                else       v = *(const f16x8*)&Knope[((size_t)h * SEQ + c0 + srow) * 128 + (p - 8) * 8];
                *(f16x8*)&Ks_[srow][p * 8] = v;
            }
            __syncthreads();

            f32x4 s[4];
#pragma unroll
            for (int ni = 0; ni < 4; ni++) {
                s[ni] = vzero;
                const f16* kp = &Ks_[ni * 16 + l15][0];
#pragma unroll
                for (int kf = 0; kf < 6; kf++)
                    s[ni] = mfma16(qf[kf], *(const f16x8*)&kp[kf * 32 + lg * 8], s[ni]);
            }

#pragma unroll
            for (int ni = 0; ni < 4; ni++) {
                const int col = c0 + ni * 16 + l15;
#pragma unroll
                for (int r = 0; r < 4; r++) {
                    const int row = rowb + lg * 4 + r;
                    l[r] += (col <= row) ? __expf(s[ni][r]) : 0.f;
                }
            }
        }
#pragma unroll
        for (int off = 1; off < 16; off <<= 1)
#pragma unroll
            for (int r = 0; r < 4; r++)
                l[r] += __shfl_xor(l[r], off);
    }

    if (l15 == 0) {
#pragma unroll
        for (int r = 0; r < 4; r++) {
            const int rin = wv * 16 + lg * 4 + r;
            lpart[(((size_t)h * 32 + qt) * KSS + ks) * 64 + rin] = l[r];
        }
    }
}

// ---------------- attention 2/2: P write (nt) + O; no K-split, complementary qt pairing ----------------
__global__ __launch_bounds__(256) void k_pv(
    const f16* __restrict__ Qf, const f16* __restrict__ Krope, const f16* __restrict__ Knope,
    const f16* __restrict__ Vt, const float* __restrict__ lpart,
    float* __restrict__ attnw,    // [16][2048][2048] final P
    f16* __restrict__ Ohead)      // [2048][16*128]
{
    const int h  = blockIdx.y;
    const int qt = (h >= 8) ? (31 - (int)blockIdx.x) : (int)blockIdx.x;
    const int q0 = qt * 64;
    const int tid = threadIdx.x;
    const int lane = tid & 63;
    const int wv = tid >> 6;
    const int l15 = lane & 15;
    const int lg  = lane >> 4;
    const int rowb = q0 + wv * 16;

    __shared__ __align__(16) f16 Ks_[64][200];
    __shared__ __align__(16) f16 Vs[128][72];
    __shared__ __align__(16) f16 Plds[4][16][72];

    f16x8 qf[6];
    {
        const f16* qbase = &Qf[((size_t)h * SEQ + rowb + l15) * 192];
#pragma unroll
        for (int kf = 0; kf < 6; kf++)
            qf[kf] = *(const f16x8*)&qbase[kf * 32 + lg * 8];
    }

    float rlr[4];
    {
        const float* base = &lpart[(((size_t)h * 32 + qt) * KSS) * 64];
#pragma unroll
        for (int r = 0; r < 4; r++) {
            const int rin = wv * 16 + lg * 4 + r;
            float ll = 0.f;
#pragma unroll
            for (int k2 = 0; k2 < KSS; k2++) ll += base[k2 * 64 + rin];
            rlr[r] = 1.f / ll;
        }
    }

    f32x4 o[8] = {};
    const f32x4 vzero = {0.f, 0.f, 0.f, 0.f};
    const int srow = tid >> 2;
    const int sp4  = tid & 3;

    for (int t = 0; t <= qt; t++) {
        const int c0 = t * 64;
        __syncthreads();
#pragma unroll
        for (int i = 0; i < 6; i++) {
            const int p = sp4 + 4 * i;
            f16x8 v;
            if (p < 8) v = *(const f16x8*)&Krope[(size_t)(c0 + srow) * 64 + p * 8];
            else       v = *(const f16x8*)&Knope[((size_t)h * SEQ + c0 + srow) * 128 + (p - 8) * 8];
            *(f16x8*)&Ks_[srow][p * 8] = v;
        }
#pragma unroll
        for (int i = 0; i < 4; i++) {
            const int c = tid + 256 * i;
            const int d = c >> 3, x = c & 7;
            *(f16x8*)&Vs[d][x * 8] = *(const f16x8*)&Vt[((size_t)h * 128 + d) * SEQ + c0 + x * 8];
        }
        __syncthreads();

        f32x4 s[4];
#pragma unroll
        for (int ni = 0; ni < 4; ni++) {
            s[ni] = vzero;
            const f16* kp = &Ks_[ni * 16 + l15][0];
#pragma unroll
            for (int kf = 0; kf < 6; kf++)
                s[ni] = mfma16(qf[kf], *(const f16x8*)&kp[kf * 32 + lg * 8], s[ni]);
        }

#pragma unroll
        for (int ni = 0; ni < 4; ni++) {
            const int col = c0 + ni * 16 + l15;
#pragma unroll
            for (int r = 0; r < 4; r++) {
                const int row = rowb + lg * 4 + r;
                float p = (col <= row) ? __expf(s[ni][r]) * rlr[r] : 0.f;
                __builtin_nontemporal_store(p, &attnw[((size_t)h * SEQ + row) * SEQ + col]);
                Plds[wv][lg * 4 + r][ni * 16 + l15] = (f16)p;
            }
        }
        asm volatile("" ::: "memory");

        f16x8 pa0 = *(const f16x8*)&Plds[wv][l15][lg * 8];
        f16x8 pa1 = *(const f16x8*)&Plds[wv][l15][32 + lg * 8];
#pragma unroll
        for (int nd = 0; nd < 8; nd++) {
            const f16* vp = &Vs[nd * 16 + l15][lg * 8];
            o[nd] = mfma16(pa0, *(const f16x8*)&vp[0],  o[nd]);
            o[nd] = mfma16(pa1, *(const f16x8*)&vp[32], o[nd]);
        }
    }

#pragma unroll
    for (int nd = 0; nd < 8; nd++)
#pragma unroll
        for (int r = 0; r < 4; r++) {
            const int row = rowb + lg * 4 + r;
            Ohead[(size_t)row * 2048 + h * 128 + nd * 16 + l15] = (f16)o[nd][r];
        }

    // zero-fill cols >= q0+64 (wave-contiguous chunk layout)
    {
        const int cstart = q0 + 64;
        const int zc = SEQ - cstart;
        if (zc > 0) {
            const int nchunk = zc >> 2;
            for (int i = tid; i < 64 * nchunk; i += 256) {
                const int r  = i / nchunk;
                const int cc = (i - r * nchunk) << 2;
                __builtin_nontemporal_store(vzero,
                    (f32x4*)&attnw[((size_t)h * SEQ + q0 + r) * SEQ + cstart + cc]);
            }
        }
    }
}

extern "C" void kernel_launch(void* const* d_in, const int* in_sizes, int n_in,
                              void* d_out, int out_size, void* d_ws, size_t ws_size,
                              hipStream_t stream)
{
    (void)in_sizes; (void)n_in; (void)out_size; (void)ws_size;
    const float* hidden    = (const float*)d_in[0];
    const float* q_down_w  = (const float*)d_in[3];
    const float* kv_down_w = (const float*)d_in[4];
    const float* q_up_w    = (const float*)d_in[5];
    const float* k_up_w    = (const float*)d_in[6];
    const float* o_w       = (const float*)d_in[7];
    const float* q_norm_w  = (const float*)d_in[8];
    const float* kv_norm_w = (const float*)d_in[9];

    float* attnw = (float*)d_out;                        // 16*2048*2048 f32
    float* outp  = attnw + (size_t)NHEAD * SEQ * SEQ;    // 2048*2048 f32

    // ---- ws layout ----
    char* wp = (char*)d_ws;
    auto aws = [&](size_t bytes) { void* p = (void*)wp; wp += (bytes + 255) & ~(size_t)255; return p; };
    f16*  ow16  = (f16*)aws((size_t)2048 * 2048 * 2);
    f16*  Ohead = (f16*)aws((size_t)2048 * 2048 * 2);
    // dead-before-o_proj region starts here (aliased by opp):
    f16*  Qf    = (f16*)aws((size_t)16 * 2048 * 192 * 2);
    f16*  Knope = (f16*)aws((size_t)16 * 2048 * 128 * 2);
    f16*  Vt    = (f16*)aws((size_t)16 * 128 * 2048 * 2);
    f16*  Krope = (f16*)aws((size_t)2048 * 64 * 2);
    float* cs   = (float*)aws((size_t)2048 * 64 * 4);
    float* lpart  = (float*)aws((size_t)16 * 32 * KSS * 64 * 4);
    f16*  opp    = (f16*)Qf;   // o_proj split-K(2) partials f16 (16.8 MB < dead region)

    // ---- early-pipeline scratch inside d_out attn region ----
    char* sp = (char*)d_out;
    auto aso = [&](size_t bytes) { void* p = (void*)sp; sp += (bytes + 255) & ~(size_t)255; return p; };
    f16*  h16      = (f16*)aso((size_t)2048 * 2048 * 2);
    f16*  dw16     = (f16*)aso((size_t)2176 * 2048 * 2);
    f16*  quw16    = (f16*)aso((size_t)3072 * 1536 * 2);
    f16*  kuw16    = (f16*)aso((size_t)4096 * 512 * 2);
    f16*  down_part = (f16*)aso((size_t)2 * 2048 * 2176 * 2);  // f16 split-K(2) partials
    f16*  cq16     = (f16*)aso((size_t)2048 * 1536 * 2);
    f16*  latent16 = (f16*)aso((size_t)2048 * 512 * 2);
    f16*  q_all    = (f16*)aso((size_t)2048 * 3072 * 2);
    f16*  kv_all   = (f16*)aso((size_t)2048 * 4096 * 2);

    // conversions + rope table, one launch (8 elems/thread)
    k_cvt_all<<<dim3(9856), dim3(256), 0, stream>>>(
        hidden, q_down_w, kv_down_w, q_up_w, k_up_w, o_w,
        h16, dw16, quw16, kuw16, ow16, cs);

    // fused down-projection, split-K=2: f16 partials [2][2048][2176]
    k_gemm<f16, false, 2><<<dim3(17, 16, 2), dim3(256), 0, stream>>>(
        h16, dw16, down_part, 2048, 2176, (size_t)2048 * 2176);

    k_rms_both<<<dim3(2048), dim3(256), 0, stream>>>(
        down_part, down_part + (size_t)2048 * 2176, q_norm_w, kv_norm_w,
        cq16, latent16, Krope, cs);

    k_up_fused<<<dim3(56, 16), dim3(256), 0, stream>>>(cq16, quw16, q_all, latent16, kuw16, kv_all);

    // fused Q-assembly + KV-assembly
    k_asm_all<<<dim3(3072 + 256), dim3(256), 0, stream>>>(q_all, cs, Qf, kv_all, Knope, Vt);

    // attention: exp-sums(KSS=4) -> P+O (single-pass K, staged V, paired qt)
    k_stats<<<dim3(32, KSS, 16), dim3(256), 0, stream>>>(Qf, Krope, Knope, lpart);
    k_pv<<<dim3(32, 16), dim3(256), 0, stream>>>(Qf, Krope, Knope, Vt, lpart, attnw, Ohead);

    // output projection, split-K=2 into f16 opp, then combine to f32 outp
    k_gemm<f16, false, 2><<<dim3(16, 16, 2), dim3(256), 0, stream>>>(
        Ohead, ow16, opp, 2048, 2048, (size_t)2048 * 2048);
    k_add2f<<<dim3(2048), dim3(256), 0, stream>>>(opp, outp);
}